// Round 9
// baseline (12447.672 us; speedup 1.0000x reference)
//
#include <hip/hip_runtime.h>
#include <hip/hip_bf16.h>

// Dims: S=512, B=32, I=768, H=256, NH=8, HD=32, ML=512
#define SDIM 512
#define BDIM 32

typedef _Float16 v2h __attribute__((ext_vector_type(2)));
typedef short bf16x8 __attribute__((ext_vector_type(8)));
typedef float f32x4 __attribute__((ext_vector_type(4)));

__device__ __forceinline__ float b2f(ushort u) {
    union { uint32_t i; float f; } v; v.i = ((uint32_t)u) << 16; return v.f;
}
__device__ __forceinline__ ushort f2b(float f) {
    union { float f; uint32_t i; } v; v.f = f;
    uint32_t u = v.i;
    return (ushort)((u + 0x7fffu + ((u >> 16) & 1u)) >> 16);  // RNE
}
__device__ __forceinline__ ushort f2h(float f) {
    union { _Float16 h; ushort u; } v; v.h = (_Float16)f; return v.u;
}
// 2 f16 MACs in one VALU op (fp32 accumulate)
__device__ __forceinline__ float dot2(uint32_t w, uint32_t h, float acc) {
#if __has_builtin(__builtin_amdgcn_fdot2)
    union { uint32_t u; v2h v; } a, b;
    a.u = w; b.u = h;
    return __builtin_amdgcn_fdot2(a.v, b.v, acc, false);
#else
    union { uint32_t u; v2h v; } a, b;
    a.u = w; b.u = h;
    return acc + (float)a.v.x * (float)b.v.x + (float)a.v.y * (float)b.v.y;
#endif
}
// fast tanh: 1 - 2/(exp(2x)+1)
__device__ __forceinline__ float ftanh(float x) {
    const float t = __expf(2.f * x);
    return 1.f - 2.f * __builtin_amdgcn_rcpf(t + 1.f);
}

// 8 f16-pairs (16 k) of CONTIGUOUS weights against packed h from LDS.
#define DCHUNK8C(WQ, HQ, ACC)                                                  \
    {                                                                          \
        uint4 wA = *(const uint4*)(WQ);                                        \
        uint4 wB = *(const uint4*)((WQ) + 4);                                  \
        uint4 hA = *(const uint4*)(HQ);                                        \
        uint4 hB = *(const uint4*)((HQ) + 4);                                  \
        ACC = dot2(wA.x, hA.x, ACC);                                           \
        ACC = dot2(wA.y, hA.y, ACC);                                           \
        ACC = dot2(wA.z, hA.z, ACC);                                           \
        ACC = dot2(wA.w, hA.w, ACC);                                           \
        ACC = dot2(wB.x, hB.x, ACC);                                           \
        ACC = dot2(wB.y, hB.y, ACC);                                           \
        ACC = dot2(wB.z, hB.z, ACC);                                           \
        ACC = dot2(wB.w, hB.w, ACC);                                           \
    }

// ---------------------------------------------------------------------------
// Pack k-major f16 pairs DIRECTLY from the untransposed weight (src[j][2p]):
// out[(p>>3)*J*8 + j*8 + (p&7)]. Thread map: p fastest -> coalesced src pairs.
// ---------------------------------------------------------------------------
__global__ __launch_bounds__(256) void pack8d_kernel(
    const float* __restrict__ src, int ld, uint32_t* __restrict__ out, int P, int J)
{
    const int idx = blockIdx.x * 256 + threadIdx.x;
    if (idx >= P * J) return;
    const int j = idx / P, p = idx - j * P;
    const ushort lo = f2h(src[(size_t)j * ld + 2 * p]);
    const ushort hi = f2h(src[(size_t)j * ld + 2 * p + 1]);
    out[(((size_t)(p >> 3) * J + j) << 3) + (p & 7)] = ((uint32_t)hi << 16) | lo;
}

// ---------------------------------------------------------------------------
// fp32 -> bf16 converts: two arrays (grid-stride) / four equal arrays
// ---------------------------------------------------------------------------
__global__ __launch_bounds__(256) void cvt_bf16x2_kernel(
    const float* __restrict__ a, ushort* __restrict__ oa, int na,
    const float* __restrict__ b, ushort* __restrict__ ob, int nb)
{
    const int stride = gridDim.x * 256;
    for (int i = blockIdx.x * 256 + threadIdx.x; i < na + nb; i += stride) {
        if (i < na) oa[i] = f2b(a[i]);
        else ob[i - na] = f2b(b[i - na]);
    }
}
__global__ __launch_bounds__(256) void cvt_bf16x4_kernel(
    const float* __restrict__ a, const float* __restrict__ b,
    const float* __restrict__ c, const float* __restrict__ d,
    ushort* __restrict__ oa, ushort* __restrict__ ob,
    ushort* __restrict__ oc, ushort* __restrict__ od, int n)
{
    const int i = blockIdx.x * 256 + threadIdx.x;
    if (i >= 4 * n) return;
    const int which = i / n, j = i - which * n;
    const float* s = which == 0 ? a : which == 1 ? b : which == 2 ? c : d;
    ushort* o = which == 0 ? oa : which == 1 ? ob : which == 2 ? oc : od;
    o[j] = f2b(s[j]);
}

// ---------------------------------------------------------------------------
// o = a + b elementwise (bias fuse: bi + bh)
// ---------------------------------------------------------------------------
__global__ __launch_bounds__(256) void addvec_kernel(
    const float* __restrict__ a, const float* __restrict__ b,
    float* __restrict__ o, int n)
{
    const int i = blockIdx.x * 256 + threadIdx.x;
    if (i < n) o[i] = a[i] + b[i];
}

// ---------------------------------------------------------------------------
// MFMA bf16 GEMM, 128x64 tile, BK=64 (16 MFMA/wave per stage, half the
// barriers of BK=32). C[m,n] = sum_k A[m,k]*B[n,k] + bias[n].
// ---------------------------------------------------------------------------
__global__ __launch_bounds__(256) void mfma_gemm128_kernel(
    const ushort* __restrict__ A16, const ushort* __restrict__ B16,
    const float* __restrict__ bias, float* __restrict__ C, int N, int K)
{
    __shared__ ushort As[128][72];   // +8 pad: 2-way-max bank aliasing
    __shared__ ushort Bs[64][72];
    const int tid = threadIdx.x;
    const int tile_m = blockIdx.x * 128, tile_n = blockIdx.y * 64;
    const int ra = tid >> 1, ca = (tid & 1) * 32;   // A: 128 rows x 64 cols
    const int rb = tid >> 2, cb = (tid & 3) * 16;   // B: 64 rows x 64 cols
    const int w = tid >> 6, lane = tid & 63;
    const int mi = lane & 15, quad = lane >> 4;
    f32x4 acc[2][4] = {};

    for (int k0 = 0; k0 < K; k0 += 64) {
        const uint4* ap = (const uint4*)(A16 + (size_t)(tile_m + ra) * K + k0 + ca);
        *(uint4*)&As[ra][ca]      = ap[0];
        *(uint4*)&As[ra][ca + 8]  = ap[1];
        *(uint4*)&As[ra][ca + 16] = ap[2];
        *(uint4*)&As[ra][ca + 24] = ap[3];
        const uint4* bp = (const uint4*)(B16 + (size_t)(tile_n + rb) * K + k0 + cb);
        *(uint4*)&Bs[rb][cb]     = bp[0];
        *(uint4*)&Bs[rb][cb + 8] = bp[1];
        __syncthreads();
        #pragma unroll
        for (int kk = 0; kk < 64; kk += 32) {
            const bf16x8 af0 = *(const bf16x8*)&As[w * 32 + mi][quad * 8 + kk];
            const bf16x8 af1 = *(const bf16x8*)&As[w * 32 + 16 + mi][quad * 8 + kk];
            #pragma unroll
            for (int j = 0; j < 4; j++) {
                const bf16x8 bf = *(const bf16x8*)&Bs[j * 16 + mi][quad * 8 + kk];
                acc[0][j] = __builtin_amdgcn_mfma_f32_16x16x32_bf16(af0, bf, acc[0][j], 0, 0, 0);
                acc[1][j] = __builtin_amdgcn_mfma_f32_16x16x32_bf16(af1, bf, acc[1][j], 0, 0, 0);
            }
        }
        __syncthreads();
    }
    #pragma unroll
    for (int j = 0; j < 4; j++) {
        const int gn = tile_n + j * 16 + mi;
        const float bv = bias[gn];
        #pragma unroll
        for (int f = 0; f < 2; f++) {
            #pragma unroll
            for (int rr = 0; rr < 4; rr++) {
                const int gm = tile_m + w * 32 + f * 16 + quad * 4 + rr;
                C[(size_t)gm * N + gn] = acc[f][j][rr] + bv;
            }
        }
    }
}

// ---------------------------------------------------------------------------
// Fused QKV GEMM, 128x64 tile, BK=64: one A-stage (ASWAP), 3 B operands,
// 48 MFMA per stage. K=N=256. relpos folded into K output.
// ---------------------------------------------------------------------------
__global__ __launch_bounds__(256) void qkv_gemm128_kernel(
    const ushort* __restrict__ A16,
    const ushort* __restrict__ Wq, const ushort* __restrict__ Wk,
    const ushort* __restrict__ Wv,
    const float* __restrict__ bq, const float* __restrict__ bk,
    const float* __restrict__ bv, const float* __restrict__ rp,
    float* __restrict__ qo, float* __restrict__ ko, float* __restrict__ vo)
{
    __shared__ ushort As[128][72];
    __shared__ ushort Bs[3][64][72];
    const int tid = threadIdx.x;
    const int tile_m = blockIdx.x * 128, tile_n = blockIdx.y * 64;
    const int ra = tid >> 1, ca = (tid & 1) * 32;
    const int am = tile_m + ra;
    const int ar = (am & (SDIM - 1)) * BDIM + (am >> 9);   // ASWAP
    const int rb = tid >> 2, cb = (tid & 3) * 16;
    const int bn = tile_n + rb;
    const int w = tid >> 6, lane = tid & 63;
    const int mi = lane & 15, quad = lane >> 4;
    f32x4 acc[3][2][4] = {};

    for (int k0 = 0; k0 < 256; k0 += 64) {
        const uint4* ap = (const uint4*)(A16 + (size_t)ar * 256 + k0 + ca);
        *(uint4*)&As[ra][ca]      = ap[0];
        *(uint4*)&As[ra][ca + 8]  = ap[1];
        *(uint4*)&As[ra][ca + 16] = ap[2];
        *(uint4*)&As[ra][ca + 24] = ap[3];
        const uint4* qp = (const uint4*)(Wq + (size_t)bn * 256 + k0 + cb);
        *(uint4*)&Bs[0][rb][cb]     = qp[0];
        *(uint4*)&Bs[0][rb][cb + 8] = qp[1];
        const uint4* kp = (const uint4*)(Wk + (size_t)bn * 256 + k0 + cb);
        *(uint4*)&Bs[1][rb][cb]     = kp[0];
        *(uint4*)&Bs[1][rb][cb + 8] = kp[1];
        const uint4* vp = (const uint4*)(Wv + (size_t)bn * 256 + k0 + cb);
        *(uint4*)&Bs[2][rb][cb]     = vp[0];
        *(uint4*)&Bs[2][rb][cb + 8] = vp[1];
        __syncthreads();
        #pragma unroll
        for (int kk = 0; kk < 64; kk += 32) {
            const bf16x8 af0 = *(const bf16x8*)&As[w * 32 + mi][quad * 8 + kk];
            const bf16x8 af1 = *(const bf16x8*)&As[w * 32 + 16 + mi][quad * 8 + kk];
            #pragma unroll
            for (int z = 0; z < 3; z++) {
                #pragma unroll
                for (int j = 0; j < 4; j++) {
                    const bf16x8 bf = *(const bf16x8*)&Bs[z][j * 16 + mi][quad * 8 + kk];
                    acc[z][0][j] = __builtin_amdgcn_mfma_f32_16x16x32_bf16(af0, bf, acc[z][0][j], 0, 0, 0);
                    acc[z][1][j] = __builtin_amdgcn_mfma_f32_16x16x32_bf16(af1, bf, acc[z][1][j], 0, 0, 0);
                }
            }
        }
        __syncthreads();
    }
    #pragma unroll
    for (int z = 0; z < 3; z++) {
        const float* bias = (z == 0) ? bq : (z == 1) ? bk : bv;
        float* out = (z == 0) ? qo : (z == 1) ? ko : vo;
        #pragma unroll
        for (int j = 0; j < 4; j++) {
            const int gn = tile_n + j * 16 + mi;
            const float bb = bias[gn];
            #pragma unroll
            for (int f = 0; f < 2; f++) {
                #pragma unroll
                for (int rr = 0; rr < 4; rr++) {
                    const int gm = tile_m + w * 32 + f * 16 + quad * 4 + rr;
                    float v = acc[z][f][j][rr] + bb;
                    if (z == 1) {
                        const int sgm = gm & (SDIM - 1);
                        v += rp[((gn >> 5) << 14) + (sgm << 5) + (gn & 31)];
                    }
                    out[(size_t)gm * 256 + gn] = v;
                }
            }
        }
    }
}

// ---------------------------------------------------------------------------
// Sequential PFN scan. Latency-structure-bound (r6/r7 falsified byte-bound):
// widen to 4 accumulator chains in the Wh and Wt matvecs so ~4 weight chunks
// are in flight per thread (scalars, not arrays -> no spill). gx loads
// prefetched at phase top. Otherwise identical to the r1 structure.
// ---------------------------------------------------------------------------
__global__ __launch_bounds__(1024) void scan_kernel(
    const float* __restrict__ gx,       // [S,B,1280] precomputed x@Wi.T+bi+bh
    const uint32_t* __restrict__ Wh8,   // [16][1280][8] f16 pairs
    const uint32_t* __restrict__ Wt8,   // [48][256][8] f16 pairs
    const float* __restrict__ bt,       // [256]
    ushort* __restrict__ h_ner,         // [S,B,256] bf16
    ushort* __restrict__ h_re)          // [S,B,256] bf16
{
    const int b = blockIdx.x;
    const int tid = threadIdx.x;
    __shared__ float cs[256], g[1280], ext[1024];
    __shared__ alignas(16) uint32_t hs_pk[128];
    __shared__ alignas(16) uint32_t cat_pk[384];
    __shared__ float rsum[16];
    if (tid < 256) cs[tid] = 0.f;
    if (tid < 128) hs_pk[tid] = 0u;
    __syncthreads();
    const int lane = tid & 63;
    const int ch = tid >> 8;            // cumsoftmax chunk 0..3
    const int wch = (tid >> 6) & 3;     // wave within chunk
    const int er = tid & 255;
    const int ep = tid >> 8;
    const uint32_t* wmain = Wh8 + (size_t)tid * 8;
    const uint32_t* wext  = Wh8 + ((size_t)(ep * 4) * 1280 + 1024 + er) * 8;
    const uint32_t* wtp   = Wt8 + ((size_t)(ep * 12) * 256 + er) * 8;

    for (int t = 0; t < SDIM; t++) {
        const float* gxr = gx + (size_t)(t * BDIM + b) * 1280;
        const float gxv = gxr[tid];                          // prefetch
        // ---- gates = gx + h @ Wh.T (rows 0..1023, 4 acc chains) ----
        {
            float a0 = 0.f, a1 = 0.f, a2 = 0.f, a3 = 0.f;
            #pragma unroll
            for (int q8 = 0; q8 < 16; q8 += 4) {
                DCHUNK8C(wmain + (size_t)q8 * 10240, hs_pk + q8 * 8, a0);
                DCHUNK8C(wmain + (size_t)(q8 + 1) * 10240, hs_pk + q8 * 8 + 8, a1);
                DCHUNK8C(wmain + (size_t)(q8 + 2) * 10240, hs_pk + q8 * 8 + 16, a2);
                DCHUNK8C(wmain + (size_t)(q8 + 3) * 10240, hs_pk + q8 * 8 + 24, a3);
            }
            g[tid] = gxv + (a0 + a1) + (a2 + a3);
        }
        {   // rows 1024..1279, k split 4 ways; ep==0 folds the gx term in
            float e0 = (ep == 0) ? gxr[1024 + er] : 0.f, e1 = 0.f;
            DCHUNK8C(wext + (size_t)0 * 10240, hs_pk + (ep * 4) * 8, e0);
            DCHUNK8C(wext + (size_t)1 * 10240, hs_pk + (ep * 4 + 1) * 8, e1);
            DCHUNK8C(wext + (size_t)2 * 10240, hs_pk + (ep * 4 + 2) * 8, e0);
            DCHUNK8C(wext + (size_t)3 * 10240, hs_pk + (ep * 4 + 3) * 8, e1);
            ext[ep * 256 + er] = e0 + e1;
        }
        __syncthreads();
        // ---- c = tanh(chunk0); cumsoftmax on chunks 1..4 (no max-sub) ----
        if (tid < 256) g[tid] = ftanh(g[tid]);
        float v;
        if (tid >= 768) {   // finish reduction for gate rows 1024..1279
            const int r_ = tid - 768;
            v = ext[r_] + ext[256 + r_] + ext[512 + r_] + ext[768 + r_];
        } else {
            v = g[256 + tid];
        }
        const float e = __expf(v);
        float wsum = e;
        #pragma unroll
        for (int off = 32; off >= 1; off >>= 1) wsum += __shfl_xor(wsum, off, 64);
        if (lane == 0) rsum[ch * 4 + wch] = wsum;
        float cum = e;   // inclusive wave scan
        #pragma unroll
        for (int off = 1; off <= 32; off <<= 1) {
            float tsh = __shfl_up(cum, (unsigned)off, 64);
            if (lane >= off) cum += tsh;
        }
        __syncthreads();
        const float tot = rsum[ch * 4] + rsum[ch * 4 + 1] + rsum[ch * 4 + 2] + rsum[ch * 4 + 3];
        float prev = 0.f;
        if (wch > 0) prev += rsum[ch * 4];
        if (wch > 1) prev += rsum[ch * 4 + 1];
        if (wch > 2) prev += rsum[ch * 4 + 2];
        float r = (cum + prev) * __builtin_amdgcn_rcpf(tot);
        if (ch == 0 || ch == 2) r = 1.f - r;   // eg_* = 1 - cumsoftmax
        g[256 + tid] = r;
        __syncthreads();
        // ---- combine gates -> c_re, c_ner, share; emit h_ner/h_re (bf16) ----
        if (tid < 256) {
            const float c = g[tid];
            const float egi = g[256 + tid], rgi = g[512 + tid];
            const float egc = g[768 + tid], rgc = g[1024 + tid];
            const float cin = cs[tid];
            const float ovc = rgc * egc, upc = rgc - ovc, dnc = egc - ovc;
            const float ovi = rgi * egi, upi = rgi - ovi, dni = egi - ovi;
            const float share = ovi * cin + ovc * c;
            const float cre = upi * cin + upc * c + share;
            const float cner = dni * cin + dnc * c + share;
            ((_Float16*)cat_pk)[tid]       = (_Float16)cre;
            ((_Float16*)cat_pk)[256 + tid] = (_Float16)cner;
            ((_Float16*)cat_pk)[512 + tid] = (_Float16)share;
            const size_t ob = (size_t)(t * BDIM + b) * 256 + tid;
            h_re[ob] = f2b(ftanh(cre));
            h_ner[ob] = f2b(ftanh(cner));
        }
        __syncthreads();
        // ---- c_out = cat @ Wt.T + bt (4 acc chains over 12 chunks) ----
        {
            float s0 = 0.f, s1 = 0.f, s2 = 0.f, s3 = 0.f;
            #pragma unroll
            for (int i = 0; i < 12; i += 4) {
                DCHUNK8C(wtp + (size_t)i * 2048, cat_pk + (ep * 12 + i) * 8, s0);
                DCHUNK8C(wtp + (size_t)(i + 1) * 2048, cat_pk + (ep * 12 + i + 1) * 8, s1);
                DCHUNK8C(wtp + (size_t)(i + 2) * 2048, cat_pk + (ep * 12 + i + 2) * 8, s2);
                DCHUNK8C(wtp + (size_t)(i + 3) * 2048, cat_pk + (ep * 12 + i + 3) * 8, s3);
            }
            g[ep * 256 + er] = (s0 + s1) + (s2 + s3);
        }
        __syncthreads();
        if (tid < 256) {
            const float co = g[tid] + g[256 + tid] + g[512 + tid] + g[768 + tid] + bt[tid];
            cs[tid] = co;
            ((_Float16*)hs_pk)[tid] = (_Float16)ftanh(co);
        }
        __syncthreads();
    }
}

// ---------------------------------------------------------------------------
// Attention for one (b, head): scores = q·(k+relpos) (relpos pre-folded into
// kk_ws), softmax, PV. Output stored bf16 for the MFMA out-projection.
// Dual accumulators in QK and PV halve the serial fmac dependency chains.
// ---------------------------------------------------------------------------
__global__ __launch_bounds__(512) void attn_kernel(
    const float* __restrict__ q_ws, const float* __restrict__ kk_ws,
    const float* __restrict__ v_ws, ushort* __restrict__ o16)
{
    __shared__ float sc[8 * 516];   // 8 q-rows x 512 probs, stride 516 (bank pad)
    __shared__ float ps[8 * 256];   // PV partials per wave
    __shared__ float sinv[8];
    const int bn = blockIdx.x;
    const int b = bn >> 3, n = bn & 7;
    const int tid = threadIdx.x;
    const int w = tid >> 6, lane = tid & 63;
    const int ki = w * 64 + lane;
    float kv[32];
    {
        const float4* kp = (const float4*)(kk_ws + (size_t)(b * 512 + ki) * 256 + n * 32);
        #pragma unroll
        for (int d4 = 0; d4 < 8; d4++) {
            float4 x = kp[d4];
            kv[4 * d4] = x.x; kv[4 * d4 + 1] = x.y; kv[4 * d4 + 2] = x.z; kv[4 * d4 + 3] = x.w;
        }
    }
    const int rr = lane >> 3, dq = lane & 7;

    for (int q0 = 0; q0 < 512; q0 += 8) {
        const float* qbase = q_ws + (size_t)(b * 512 + q0) * 256 + n * 32;
        #pragma unroll 1
        for (int r = 0; r < 8; r++) {
            const float4* q4 = (const float4*)(qbase + r * 256);   // wave-uniform
            float s0 = 0.f, s1 = 0.f;
            #pragma unroll
            for (int d4 = 0; d4 < 8; d4 += 2) {
                const float4 qa = q4[d4];
                const float4 qb = q4[d4 + 1];
                s0 += qa.x * kv[4 * d4] + qa.y * kv[4 * d4 + 1]
                    + qa.z * kv[4 * d4 + 2] + qa.w * kv[4 * d4 + 3];
                s1 += qb.x * kv[4 * d4 + 4] + qb.y * kv[4 * d4 + 5]
                    + qb.z * kv[4 * d4 + 6] + qb.w * kv[4 * d4 + 7];
            }
            sc[r * 516 + ki] = s0 + s1;
        }
        __syncthreads();
        // softmax of row w by wave w
        {
            float* row = sc + w * 516;
            float4 a = ((const float4*)row)[lane];
            float4 c4 = ((const float4*)row)[lane + 64];
            float mx = fmaxf(fmaxf(fmaxf(a.x, a.y), fmaxf(a.z, a.w)),
                             fmaxf(fmaxf(c4.x, c4.y), fmaxf(c4.z, c4.w)));
            #pragma unroll
            for (int off = 32; off >= 1; off >>= 1) mx = fmaxf(mx, __shfl_xor(mx, off, 64));
            a.x = __expf(a.x - mx); a.y = __expf(a.y - mx);
            a.z = __expf(a.z - mx); a.w = __expf(a.w - mx);
            c4.x = __expf(c4.x - mx); c4.y = __expf(c4.y - mx);
            c4.z = __expf(c4.z - mx); c4.w = __expf(c4.w - mx);
            float sm = a.x + a.y + a.z + a.w + c4.x + c4.y + c4.z + c4.w;
            #pragma unroll
            for (int off = 32; off >= 1; off >>= 1) sm += __shfl_xor(sm, off, 64);
            ((float4*)row)[lane] = a;
            ((float4*)row)[lane + 64] = c4;
            if (lane == 0) sinv[w] = 1.f / sm;
        }
        __syncthreads();
        // PV: wave w covers ki in [w*64, w*64+64); lane -> (row rr, 4 dims dq*4)
        {
            float4 acc0 = {0.f, 0.f, 0.f, 0.f};
            float4 acc1 = {0.f, 0.f, 0.f, 0.f};
            const float* erow = sc + rr * 516 + w * 64;
            const float* vbase = v_ws + (size_t)(b * 512 + w * 64) * 256 + n * 32 + dq * 4;
            #pragma unroll 4
            for (int j = 0; j < 64; j += 2) {
                const float e0 = erow[j], e1 = erow[j + 1];
                float4 v0 = *(const float4*)(vbase + (size_t)j * 256);
                float4 v1 = *(const float4*)(vbase + (size_t)(j + 1) * 256);
                acc0.x += e0 * v0.x; acc0.y += e0 * v0.y;
                acc0.z += e0 * v0.z; acc0.w += e0 * v0.w;
                acc1.x += e1 * v1.x; acc1.y += e1 * v1.y;
                acc1.z += e1 * v1.z; acc1.w += e1 * v1.w;
            }
            float4 acc = {acc0.x + acc1.x, acc0.y + acc1.y,
                          acc0.z + acc1.z, acc0.w + acc1.w};
            ((float4*)ps)[tid] = acc;
        }
        __syncthreads();
        if (tid < 256) {
            const int r2 = tid >> 5, d = tid & 31;
            float s = 0.f;
            #pragma unroll
            for (int ww = 0; ww < 8; ww++) s += ps[ww * 256 + r2 * 32 + d];
            o16[(size_t)(b * 512 + q0 + r2) * 256 + n * 32 + d] = f2b(s * sinv[r2]);
        }
        __syncthreads();
    }
}

// ---------------------------------------------------------------------------
// y = LN(hb + proj) -> fp32 output in [S,B,H] order (residual hb is bf16)
// ---------------------------------------------------------------------------
__global__ __launch_bounds__(256) void ln_kernel(
    const float* __restrict__ proj, const ushort* __restrict__ hsrc,
    const float* __restrict__ lng, const float* __restrict__ lnb,
    float* __restrict__ outp)
{
    const int m = blockIdx.x;           // b*512 + s
    const int j = threadIdx.x;
    const int b = m >> 9, s = m & 511;
    const size_t oidx = (size_t)(s * 32 + b) * 256 + j;
    const float y = proj[(size_t)m * 256 + j] + b2f(hsrc[oidx]);
    float sum = y, sq = y * y;
    #pragma unroll
    for (int off = 32; off >= 1; off >>= 1) {
        sum += __shfl_xor(sum, off, 64);
        sq += __shfl_xor(sq, off, 64);
    }
    __shared__ float r1[4], r2[4];
    const int wv = j >> 6;
    if ((j & 63) == 0) { r1[wv] = sum; r2[wv] = sq; }
    __syncthreads();
    const float ts = r1[0] + r1[1] + r1[2] + r1[3];
    const float tq = r2[0] + r2[1] + r2[2] + r2[3];
    const float mean = ts * (1.f / 256.f);
    const float var = tq * (1.f / 256.f) - mean * mean;
    const float o = (y - mean) * rsqrtf(var + 1e-5f) * lng[j] + lnb[j];
    outp[oidx] = o;
}

extern "C" void kernel_launch(void* const* d_in, const int* in_sizes, int n_in,
                              void* d_out, int out_size, void* d_ws, size_t ws_size,
                              hipStream_t stream) {
    (void)in_sizes; (void)n_in; (void)out_size; (void)ws_size;
    const float* x   = (const float*)d_in[0];
    const float* Wi  = (const float*)d_in[1];
    const float* bi  = (const float*)d_in[2];
    const float* Wh  = (const float*)d_in[3];
    const float* bh  = (const float*)d_in[4];
    const float* Wt  = (const float*)d_in[5];
    const float* bt  = (const float*)d_in[6];
    const float* Wq  = (const float*)d_in[7];
    const float* bq  = (const float*)d_in[8];
    const float* Wk  = (const float*)d_in[9];
    const float* bk  = (const float*)d_in[10];
    const float* Wv  = (const float*)d_in[11];
    const float* bv  = (const float*)d_in[12];
    const float* Wo  = (const float*)d_in[13];
    const float* bo  = (const float*)d_in[14];
    const float* rp  = (const float*)d_in[15];
    const float* lng = (const float*)d_in[16];
    const float* lnb = (const float*)d_in[17];
    float* outp = (float*)d_out;

    float* ws = (float*)d_ws;
    // pool [0, 20971520): gx fp32 [16384,1280] during pre-scan/scan; attention
    // scratch afterwards (q/kk/v fp32, pj fp32, o16 bf16).
    float* gx    = ws;
    float* q_ws  = ws;
    float* kk_ws = ws + 4194304;
    float* v_ws  = ws + 8388608;
    float* pj_ws = ws + 12582912;
    ushort* o16  = (ushort*)(ws + 16777216);     // [16384,256] bf16
    ushort* hner16 = (ushort*)(ws + 20971520);   // [S,B,256] bf16
    ushort* hre16  = (ushort*)(ws + 23068672);
    uint32_t* Wh8 = (uint32_t*)(ws + 25165824);  // [16][1280][8] f16 pairs
    uint32_t* Wt8 = (uint32_t*)(ws + 25329664);  // [48][256][8] f16 pairs
    ushort* Wq16 = (ushort*)(ws + 25427968);     // [3,256,256] bf16
    ushort* Wk16 = (ushort*)(ws + 25526272);
    ushort* Wv16 = (ushort*)(ws + 25624576);
    ushort* Wo16 = (ushort*)(ws + 25722880);     // ends 25821184 (<= r5 footprint)

    // d_out doubles as pre-scan scratch (validated only after final ln writes):
    ushort* x16  = (ushort*)outp;                // [16384,768] bf16 (6291456 f)
    ushort* Wi16 = (ushort*)(outp + 6291456);    // [1280,768] bf16 (491520 f)
    float* bsum  = outp + 7307264;               // [1280] fp32 (bi + bh)

    // 0) weight prep: direct f16 packs (no transpose pass) + bf16 GEMM operands
    pack8d_kernel<<<dim3(640), 256, 0, stream>>>(Wh, 256, Wh8, 128, 1280);
    pack8d_kernel<<<dim3(384), 256, 0, stream>>>(Wt, 768, Wt8, 384, 256);
    addvec_kernel<<<dim3(5), 256, 0, stream>>>(bi, bh, bsum, 1280);
    cvt_bf16x2_kernel<<<dim3(4096), 256, 0, stream>>>(x, x16, 12582912, Wi, Wi16, 983040);
    cvt_bf16x4_kernel<<<dim3(3072), 256, 0, stream>>>(
        Wq, Wk, Wv, Wo, Wq16, Wk16, Wv16, Wo16, 196608);

    // 1) gates_x = x @ Wi.T + (bi + bh)   [16384,1280]  (MFMA, 128x64, BK=64)
    mfma_gemm128_kernel<<<dim3(128, 20), 256, 0, stream>>>(
        x16, Wi16, bsum, gx, 1280, 768);

    // 2) sequential scan (one block per batch element)
    scan_kernel<<<dim3(32), dim3(1024), 0, stream>>>(gx, Wh8, Wt8, bt, hner16, hre16);

    // 3) three attentions: (h_ner,0), (h_re,1), (h_re,2)
    for (int i = 0; i < 3; i++) {
        const ushort* src16 = (i == 0) ? hner16 : hre16;
        qkv_gemm128_kernel<<<dim3(128, 4), 256, 0, stream>>>(
            src16, Wq16 + (size_t)i * 65536, Wk16 + (size_t)i * 65536,
            Wv16 + (size_t)i * 65536, bq + i * 256, bk + i * 256, bv + i * 256,
            rp + (size_t)i * 131072, q_ws, kk_ws, v_ws);
        attn_kernel<<<dim3(256), dim3(512), 0, stream>>>(q_ws, kk_ws, v_ws, o16);
        mfma_gemm128_kernel<<<dim3(128, 4), 256, 0, stream>>>(
            o16, Wo16 + (size_t)i * 65536, bo + i * 256, pj_ws, 256, 256);
        ln_kernel<<<dim3(16384), dim3(256), 0, stream>>>(
            pj_ws, src16, lng, lnb, outp + (size_t)i * 4194304);
    }
}

// Round 10
// 5925.670 us; speedup vs baseline: 2.1006x; 2.1006x over previous
//
#include <hip/hip_runtime.h>
#include <hip/hip_bf16.h>

// Dims: S=512, B=32, I=768, H=256, NH=8, HD=32, ML=512
#define SDIM 512
#define BDIM 32

typedef _Float16 v2h __attribute__((ext_vector_type(2)));
typedef short bf16x8 __attribute__((ext_vector_type(8)));
typedef float f32x4 __attribute__((ext_vector_type(4)));

__device__ __forceinline__ float b2f(ushort u) {
    union { uint32_t i; float f; } v; v.i = ((uint32_t)u) << 16; return v.f;
}
__device__ __forceinline__ ushort f2b(float f) {
    union { float f; uint32_t i; } v; v.f = f;
    uint32_t u = v.i;
    return (ushort)((u + 0x7fffu + ((u >> 16) & 1u)) >> 16);  // RNE
}
__device__ __forceinline__ ushort f2h(float f) {
    union { _Float16 h; ushort u; } v; v.h = (_Float16)f; return v.u;
}
// 2 f16 MACs in one VALU op (fp32 accumulate)
__device__ __forceinline__ float dot2(uint32_t w, uint32_t h, float acc) {
#if __has_builtin(__builtin_amdgcn_fdot2)
    union { uint32_t u; v2h v; } a, b;
    a.u = w; b.u = h;
    return __builtin_amdgcn_fdot2(a.v, b.v, acc, false);
#else
    union { uint32_t u; v2h v; } a, b;
    a.u = w; b.u = h;
    return acc + (float)a.v.x * (float)b.v.x + (float)a.v.y * (float)b.v.y;
#endif
}
// fast tanh: 1 - 2/(exp(2x)+1)
__device__ __forceinline__ float ftanh(float x) {
    const float t = __expf(2.f * x);
    return 1.f - 2.f * __builtin_amdgcn_rcpf(t + 1.f);
}

// 8 f16-pairs (16 k) of CONTIGUOUS weights against packed h from LDS.
#define DCHUNK8C(WQ, HQ, ACC)                                                  \
    {                                                                          \
        uint4 wA = *(const uint4*)(WQ);                                        \
        uint4 wB = *(const uint4*)((WQ) + 4);                                  \
        uint4 hA = *(const uint4*)(HQ);                                        \
        uint4 hB = *(const uint4*)((HQ) + 4);                                  \
        ACC = dot2(wA.x, hA.x, ACC);                                           \
        ACC = dot2(wA.y, hA.y, ACC);                                           \
        ACC = dot2(wA.z, hA.z, ACC);                                           \
        ACC = dot2(wA.w, hA.w, ACC);                                           \
        ACC = dot2(wB.x, hB.x, ACC);                                           \
        ACC = dot2(wB.y, hB.y, ACC);                                           \
        ACC = dot2(wB.z, hB.z, ACC);                                           \
        ACC = dot2(wB.w, hB.w, ACC);                                           \
    }

// ---------------------------------------------------------------------------
// Pack k-major f16 pairs DIRECTLY from the untransposed weight (src[j][2p]):
// out[(p>>3)*J*8 + j*8 + (p&7)]. Thread map: p fastest -> coalesced src pairs.
// ---------------------------------------------------------------------------
__global__ __launch_bounds__(256) void pack8d_kernel(
    const float* __restrict__ src, int ld, uint32_t* __restrict__ out, int P, int J)
{
    const int idx = blockIdx.x * 256 + threadIdx.x;
    if (idx >= P * J) return;
    const int j = idx / P, p = idx - j * P;
    const ushort lo = f2h(src[(size_t)j * ld + 2 * p]);
    const ushort hi = f2h(src[(size_t)j * ld + 2 * p + 1]);
    out[(((size_t)(p >> 3) * J + j) << 3) + (p & 7)] = ((uint32_t)hi << 16) | lo;
}

// ---------------------------------------------------------------------------
// fp32 -> bf16 converts: two arrays (grid-stride) / four equal arrays
// ---------------------------------------------------------------------------
__global__ __launch_bounds__(256) void cvt_bf16x2_kernel(
    const float* __restrict__ a, ushort* __restrict__ oa, int na,
    const float* __restrict__ b, ushort* __restrict__ ob, int nb)
{
    const int stride = gridDim.x * 256;
    for (int i = blockIdx.x * 256 + threadIdx.x; i < na + nb; i += stride) {
        if (i < na) oa[i] = f2b(a[i]);
        else ob[i - na] = f2b(b[i - na]);
    }
}
__global__ __launch_bounds__(256) void cvt_bf16x4_kernel(
    const float* __restrict__ a, const float* __restrict__ b,
    const float* __restrict__ c, const float* __restrict__ d,
    ushort* __restrict__ oa, ushort* __restrict__ ob,
    ushort* __restrict__ oc, ushort* __restrict__ od, int n)
{
    const int i = blockIdx.x * 256 + threadIdx.x;
    if (i >= 4 * n) return;
    const int which = i / n, j = i - which * n;
    const float* s = which == 0 ? a : which == 1 ? b : which == 2 ? c : d;
    ushort* o = which == 0 ? oa : which == 1 ? ob : which == 2 ? oc : od;
    o[j] = f2b(s[j]);
}

// ---------------------------------------------------------------------------
// o = a + b elementwise (bias fuse: bi + bh)
// ---------------------------------------------------------------------------
__global__ __launch_bounds__(256) void addvec_kernel(
    const float* __restrict__ a, const float* __restrict__ b,
    float* __restrict__ o, int n)
{
    const int i = blockIdx.x * 256 + threadIdx.x;
    if (i < n) o[i] = a[i] + b[i];
}

// ---------------------------------------------------------------------------
// MFMA bf16 GEMM, 128x64 tile, BK=64 (16 MFMA/wave per stage, half the
// barriers of BK=32). C[m,n] = sum_k A[m,k]*B[n,k] + bias[n].
// ---------------------------------------------------------------------------
__global__ __launch_bounds__(256) void mfma_gemm128_kernel(
    const ushort* __restrict__ A16, const ushort* __restrict__ B16,
    const float* __restrict__ bias, float* __restrict__ C, int N, int K)
{
    __shared__ ushort As[128][72];   // +8 pad: 2-way-max bank aliasing
    __shared__ ushort Bs[64][72];
    const int tid = threadIdx.x;
    const int tile_m = blockIdx.x * 128, tile_n = blockIdx.y * 64;
    const int ra = tid >> 1, ca = (tid & 1) * 32;   // A: 128 rows x 64 cols
    const int rb = tid >> 2, cb = (tid & 3) * 16;   // B: 64 rows x 64 cols
    const int w = tid >> 6, lane = tid & 63;
    const int mi = lane & 15, quad = lane >> 4;
    f32x4 acc[2][4] = {};

    for (int k0 = 0; k0 < K; k0 += 64) {
        const uint4* ap = (const uint4*)(A16 + (size_t)(tile_m + ra) * K + k0 + ca);
        *(uint4*)&As[ra][ca]      = ap[0];
        *(uint4*)&As[ra][ca + 8]  = ap[1];
        *(uint4*)&As[ra][ca + 16] = ap[2];
        *(uint4*)&As[ra][ca + 24] = ap[3];
        const uint4* bp = (const uint4*)(B16 + (size_t)(tile_n + rb) * K + k0 + cb);
        *(uint4*)&Bs[rb][cb]     = bp[0];
        *(uint4*)&Bs[rb][cb + 8] = bp[1];
        __syncthreads();
        #pragma unroll
        for (int kk = 0; kk < 64; kk += 32) {
            const bf16x8 af0 = *(const bf16x8*)&As[w * 32 + mi][quad * 8 + kk];
            const bf16x8 af1 = *(const bf16x8*)&As[w * 32 + 16 + mi][quad * 8 + kk];
            #pragma unroll
            for (int j = 0; j < 4; j++) {
                const bf16x8 bf = *(const bf16x8*)&Bs[j * 16 + mi][quad * 8 + kk];
                acc[0][j] = __builtin_amdgcn_mfma_f32_16x16x32_bf16(af0, bf, acc[0][j], 0, 0, 0);
                acc[1][j] = __builtin_amdgcn_mfma_f32_16x16x32_bf16(af1, bf, acc[1][j], 0, 0, 0);
            }
        }
        __syncthreads();
    }
    #pragma unroll
    for (int j = 0; j < 4; j++) {
        const int gn = tile_n + j * 16 + mi;
        const float bv = bias[gn];
        #pragma unroll
        for (int f = 0; f < 2; f++) {
            #pragma unroll
            for (int rr = 0; rr < 4; rr++) {
                const int gm = tile_m + w * 32 + f * 16 + quad * 4 + rr;
                C[(size_t)gm * N + gn] = acc[f][j][rr] + bv;
            }
        }
    }
}

// ---------------------------------------------------------------------------
// Fused QKV GEMM, 128x64 tile, BK=64: one A-stage (ASWAP), 3 B operands,
// 48 MFMA per stage. K=N=256. relpos folded into K output.
// ---------------------------------------------------------------------------
__global__ __launch_bounds__(256) void qkv_gemm128_kernel(
    const ushort* __restrict__ A16,
    const ushort* __restrict__ Wq, const ushort* __restrict__ Wk,
    const ushort* __restrict__ Wv,
    const float* __restrict__ bq, const float* __restrict__ bk,
    const float* __restrict__ bv, const float* __restrict__ rp,
    float* __restrict__ qo, float* __restrict__ ko, float* __restrict__ vo)
{
    __shared__ ushort As[128][72];
    __shared__ ushort Bs[3][64][72];
    const int tid = threadIdx.x;
    const int tile_m = blockIdx.x * 128, tile_n = blockIdx.y * 64;
    const int ra = tid >> 1, ca = (tid & 1) * 32;
    const int am = tile_m + ra;
    const int ar = (am & (SDIM - 1)) * BDIM + (am >> 9);   // ASWAP
    const int rb = tid >> 2, cb = (tid & 3) * 16;
    const int bn = tile_n + rb;
    const int w = tid >> 6, lane = tid & 63;
    const int mi = lane & 15, quad = lane >> 4;
    f32x4 acc[3][2][4] = {};

    for (int k0 = 0; k0 < 256; k0 += 64) {
        const uint4* ap = (const uint4*)(A16 + (size_t)ar * 256 + k0 + ca);
        *(uint4*)&As[ra][ca]      = ap[0];
        *(uint4*)&As[ra][ca + 8]  = ap[1];
        *(uint4*)&As[ra][ca + 16] = ap[2];
        *(uint4*)&As[ra][ca + 24] = ap[3];
        const uint4* qp = (const uint4*)(Wq + (size_t)bn * 256 + k0 + cb);
        *(uint4*)&Bs[0][rb][cb]     = qp[0];
        *(uint4*)&Bs[0][rb][cb + 8] = qp[1];
        const uint4* kp = (const uint4*)(Wk + (size_t)bn * 256 + k0 + cb);
        *(uint4*)&Bs[1][rb][cb]     = kp[0];
        *(uint4*)&Bs[1][rb][cb + 8] = kp[1];
        const uint4* vp = (const uint4*)(Wv + (size_t)bn * 256 + k0 + cb);
        *(uint4*)&Bs[2][rb][cb]     = vp[0];
        *(uint4*)&Bs[2][rb][cb + 8] = vp[1];
        __syncthreads();
        #pragma unroll
        for (int kk = 0; kk < 64; kk += 32) {
            const bf16x8 af0 = *(const bf16x8*)&As[w * 32 + mi][quad * 8 + kk];
            const bf16x8 af1 = *(const bf16x8*)&As[w * 32 + 16 + mi][quad * 8 + kk];
            #pragma unroll
            for (int z = 0; z < 3; z++) {
                #pragma unroll
                for (int j = 0; j < 4; j++) {
                    const bf16x8 bf = *(const bf16x8*)&Bs[z][j * 16 + mi][quad * 8 + kk];
                    acc[z][0][j] = __builtin_amdgcn_mfma_f32_16x16x32_bf16(af0, bf, acc[z][0][j], 0, 0, 0);
                    acc[z][1][j] = __builtin_amdgcn_mfma_f32_16x16x32_bf16(af1, bf, acc[z][1][j], 0, 0, 0);
                }
            }
        }
        __syncthreads();
    }
    #pragma unroll
    for (int z = 0; z < 3; z++) {
        const float* bias = (z == 0) ? bq : (z == 1) ? bk : bv;
        float* out = (z == 0) ? qo : (z == 1) ? ko : vo;
        #pragma unroll
        for (int j = 0; j < 4; j++) {
            const int gn = tile_n + j * 16 + mi;
            const float bb = bias[gn];
            #pragma unroll
            for (int f = 0; f < 2; f++) {
                #pragma unroll
                for (int rr = 0; rr < 4; rr++) {
                    const int gm = tile_m + w * 32 + f * 16 + quad * 4 + rr;
                    float v = acc[z][f][j][rr] + bb;
                    if (z == 1) {
                        const int sgm = gm & (SDIM - 1);
                        v += rp[((gn >> 5) << 14) + (sgm << 5) + (gn & 31)];
                    }
                    out[(size_t)gm * 256 + gn] = v;
                }
            }
        }
    }
}

// ---------------------------------------------------------------------------
// Sequential PFN scan — r1-EXACT structure (proven 4.19 ms; structural floor).
// Falsified alternatives: cross-CU split (r3, sync-latency), register stash
// (r2/r6/r9, all spill at the 64-VGPR allocator cap), LDS stash (r7, null).
// DO NOT raise live-register demand in this kernel.
// ---------------------------------------------------------------------------
__global__ __launch_bounds__(1024) void scan_kernel(
    const float* __restrict__ gx,       // [S,B,1280] precomputed x@Wi.T+bi+bh
    const uint32_t* __restrict__ Wh8,   // [16][1280][8] f16 pairs
    const uint32_t* __restrict__ Wt8,   // [48][256][8] f16 pairs
    const float* __restrict__ bt,       // [256]
    ushort* __restrict__ h_ner,         // [S,B,256] bf16
    ushort* __restrict__ h_re)          // [S,B,256] bf16
{
    const int b = blockIdx.x;
    const int tid = threadIdx.x;
    __shared__ float cs[256], g[1280], ext[1024];
    __shared__ alignas(16) uint32_t hs_pk[128];
    __shared__ alignas(16) uint32_t cat_pk[384];
    __shared__ float rsum[16];
    if (tid < 256) cs[tid] = 0.f;
    if (tid < 128) hs_pk[tid] = 0u;
    __syncthreads();
    const int lane = tid & 63;
    const int ch = tid >> 8;            // cumsoftmax chunk 0..3
    const int wch = (tid >> 6) & 3;     // wave within chunk
    const int er = tid & 255;
    const int ep = tid >> 8;
    const uint32_t* wmain = Wh8 + (size_t)tid * 8;
    const uint32_t* wext  = Wh8 + ((size_t)(ep * 4) * 1280 + 1024 + er) * 8;
    const uint32_t* wtp   = Wt8 + ((size_t)(ep * 12) * 256 + er) * 8;

    for (int t = 0; t < SDIM; t++) {
        const float* gxr = gx + (size_t)(t * BDIM + b) * 1280;
        // ---- gates = gx + h @ Wh.T (rows 0..1023, full k per thread) ----
        {
            float a0 = 0.f, a1 = 0.f;
            #pragma unroll 2
            for (int q8 = 0; q8 < 16; q8 += 2) {
                DCHUNK8C(wmain + (size_t)q8 * (1280 * 8), hs_pk + q8 * 8, a0);
                DCHUNK8C(wmain + (size_t)(q8 + 1) * (1280 * 8), hs_pk + q8 * 8 + 8, a1);
            }
            g[tid] = gxr[tid] + a0 + a1;
        }
        {   // rows 1024..1279, k split 4 ways; ep==0 folds the gx term in
            float ae = (ep == 0) ? gxr[1024 + er] : 0.f;
            #pragma unroll
            for (int i = 0; i < 4; i++)
                DCHUNK8C(wext + (size_t)i * (1280 * 8), hs_pk + (ep * 4 + i) * 8, ae);
            ext[ep * 256 + er] = ae;
        }
        __syncthreads();
        // ---- c = tanh(chunk0); cumsoftmax on chunks 1..4 (no max-sub) ----
        if (tid < 256) g[tid] = ftanh(g[tid]);
        float v;
        if (tid >= 768) {   // finish reduction for gate rows 1024..1279
            const int r_ = tid - 768;
            v = ext[r_] + ext[256 + r_] + ext[512 + r_] + ext[768 + r_];
        } else {
            v = g[256 + tid];
        }
        const float e = __expf(v);
        float wsum = e;
        #pragma unroll
        for (int off = 32; off >= 1; off >>= 1) wsum += __shfl_xor(wsum, off, 64);
        if (lane == 0) rsum[ch * 4 + wch] = wsum;
        float cum = e;   // inclusive wave scan
        #pragma unroll
        for (int off = 1; off <= 32; off <<= 1) {
            float tsh = __shfl_up(cum, (unsigned)off, 64);
            if (lane >= off) cum += tsh;
        }
        __syncthreads();
        const float tot = rsum[ch * 4] + rsum[ch * 4 + 1] + rsum[ch * 4 + 2] + rsum[ch * 4 + 3];
        float prev = 0.f;
        if (wch > 0) prev += rsum[ch * 4];
        if (wch > 1) prev += rsum[ch * 4 + 1];
        if (wch > 2) prev += rsum[ch * 4 + 2];
        float r = (cum + prev) * __builtin_amdgcn_rcpf(tot);
        if (ch == 0 || ch == 2) r = 1.f - r;   // eg_* = 1 - cumsoftmax
        g[256 + tid] = r;
        __syncthreads();
        // ---- combine gates -> c_re, c_ner, share; emit h_ner/h_re (bf16) ----
        if (tid < 256) {
            const float c = g[tid];
            const float egi = g[256 + tid], rgi = g[512 + tid];
            const float egc = g[768 + tid], rgc = g[1024 + tid];
            const float cin = cs[tid];
            const float ovc = rgc * egc, upc = rgc - ovc, dnc = egc - ovc;
            const float ovi = rgi * egi, upi = rgi - ovi, dni = egi - ovi;
            const float share = ovi * cin + ovc * c;
            const float cre = upi * cin + upc * c + share;
            const float cner = dni * cin + dnc * c + share;
            ((_Float16*)cat_pk)[tid]       = (_Float16)cre;
            ((_Float16*)cat_pk)[256 + tid] = (_Float16)cner;
            ((_Float16*)cat_pk)[512 + tid] = (_Float16)share;
            const size_t ob = (size_t)(t * BDIM + b) * 256 + tid;
            h_re[ob] = f2b(ftanh(cre));
            h_ner[ob] = f2b(ftanh(cner));
        }
        __syncthreads();
        // ---- c_out = cat @ Wt.T + bt (4 k-partials of 96 pairs per output) ----
        {
            float s0 = 0.f, s1 = 0.f;
            #pragma unroll 2
            for (int i = 0; i < 12; i += 2) {
                DCHUNK8C(wtp + (size_t)i * (256 * 8), cat_pk + (ep * 12 + i) * 8, s0);
                DCHUNK8C(wtp + (size_t)(i + 1) * (256 * 8), cat_pk + (ep * 12 + i + 1) * 8, s1);
            }
            g[ep * 256 + er] = s0 + s1;
        }
        __syncthreads();
        if (tid < 256) {
            const float co = g[tid] + g[256 + tid] + g[512 + tid] + g[768 + tid] + bt[tid];
            cs[tid] = co;
            ((_Float16*)hs_pk)[tid] = (_Float16)ftanh(co);
        }
        __syncthreads();
    }
}

// ---------------------------------------------------------------------------
// Attention for one (b, head): scores = q·(k+relpos) (relpos pre-folded into
// kk_ws), softmax, PV. Output stored bf16 for the MFMA out-projection.
// Dual accumulators in QK and PV halve the serial fmac dependency chains.
// ---------------------------------------------------------------------------
__global__ __launch_bounds__(512) void attn_kernel(
    const float* __restrict__ q_ws, const float* __restrict__ kk_ws,
    const float* __restrict__ v_ws, ushort* __restrict__ o16)
{
    __shared__ float sc[8 * 516];   // 8 q-rows x 512 probs, stride 516 (bank pad)
    __shared__ float ps[8 * 256];   // PV partials per wave
    __shared__ float sinv[8];
    const int bn = blockIdx.x;
    const int b = bn >> 3, n = bn & 7;
    const int tid = threadIdx.x;
    const int w = tid >> 6, lane = tid & 63;
    const int ki = w * 64 + lane;
    float kv[32];
    {
        const float4* kp = (const float4*)(kk_ws + (size_t)(b * 512 + ki) * 256 + n * 32);
        #pragma unroll
        for (int d4 = 0; d4 < 8; d4++) {
            float4 x = kp[d4];
            kv[4 * d4] = x.x; kv[4 * d4 + 1] = x.y; kv[4 * d4 + 2] = x.z; kv[4 * d4 + 3] = x.w;
        }
    }
    const int rr = lane >> 3, dq = lane & 7;

    for (int q0 = 0; q0 < 512; q0 += 8) {
        const float* qbase = q_ws + (size_t)(b * 512 + q0) * 256 + n * 32;
        #pragma unroll 1
        for (int r = 0; r < 8; r++) {
            const float4* q4 = (const float4*)(qbase + r * 256);   // wave-uniform
            float s0 = 0.f, s1 = 0.f;
            #pragma unroll
            for (int d4 = 0; d4 < 8; d4 += 2) {
                const float4 qa = q4[d4];
                const float4 qb = q4[d4 + 1];
                s0 += qa.x * kv[4 * d4] + qa.y * kv[4 * d4 + 1]
                    + qa.z * kv[4 * d4 + 2] + qa.w * kv[4 * d4 + 3];
                s1 += qb.x * kv[4 * d4 + 4] + qb.y * kv[4 * d4 + 5]
                    + qb.z * kv[4 * d4 + 6] + qb.w * kv[4 * d4 + 7];
            }
            sc[r * 516 + ki] = s0 + s1;
        }
        __syncthreads();
        // softmax of row w by wave w
        {
            float* row = sc + w * 516;
            float4 a = ((const float4*)row)[lane];
            float4 c4 = ((const float4*)row)[lane + 64];
            float mx = fmaxf(fmaxf(fmaxf(a.x, a.y), fmaxf(a.z, a.w)),
                             fmaxf(fmaxf(c4.x, c4.y), fmaxf(c4.z, c4.w)));
            #pragma unroll
            for (int off = 32; off >= 1; off >>= 1) mx = fmaxf(mx, __shfl_xor(mx, off, 64));
            a.x = __expf(a.x - mx); a.y = __expf(a.y - mx);
            a.z = __expf(a.z - mx); a.w = __expf(a.w - mx);
            c4.x = __expf(c4.x - mx); c4.y = __expf(c4.y - mx);
            c4.z = __expf(c4.z - mx); c4.w = __expf(c4.w - mx);
            float sm = a.x + a.y + a.z + a.w + c4.x + c4.y + c4.z + c4.w;
            #pragma unroll
            for (int off = 32; off >= 1; off >>= 1) sm += __shfl_xor(sm, off, 64);
            ((float4*)row)[lane] = a;
            ((float4*)row)[lane + 64] = c4;
            if (lane == 0) sinv[w] = 1.f / sm;
        }
        __syncthreads();
        // PV: wave w covers ki in [w*64, w*64+64); lane -> (row rr, 4 dims dq*4)
        {
            float4 acc0 = {0.f, 0.f, 0.f, 0.f};
            float4 acc1 = {0.f, 0.f, 0.f, 0.f};
            const float* erow = sc + rr * 516 + w * 64;
            const float* vbase = v_ws + (size_t)(b * 512 + w * 64) * 256 + n * 32 + dq * 4;
            #pragma unroll 4
            for (int j = 0; j < 64; j += 2) {
                const float e0 = erow[j], e1 = erow[j + 1];
                float4 v0 = *(const float4*)(vbase + (size_t)j * 256);
                float4 v1 = *(const float4*)(vbase + (size_t)(j + 1) * 256);
                acc0.x += e0 * v0.x; acc0.y += e0 * v0.y;
                acc0.z += e0 * v0.z; acc0.w += e0 * v0.w;
                acc1.x += e1 * v1.x; acc1.y += e1 * v1.y;
                acc1.z += e1 * v1.z; acc1.w += e1 * v1.w;
            }
            float4 acc = {acc0.x + acc1.x, acc0.y + acc1.y,
                          acc0.z + acc1.z, acc0.w + acc1.w};
            ((float4*)ps)[tid] = acc;
        }
        __syncthreads();
        if (tid < 256) {
            const int r2 = tid >> 5, d = tid & 31;
            float s = 0.f;
            #pragma unroll
            for (int ww = 0; ww < 8; ww++) s += ps[ww * 256 + r2 * 32 + d];
            o16[(size_t)(b * 512 + q0 + r2) * 256 + n * 32 + d] = f2b(s * sinv[r2]);
        }
        __syncthreads();
    }
}

// ---------------------------------------------------------------------------
// y = LN(hb + proj) -> fp32 output in [S,B,H] order (residual hb is bf16)
// ---------------------------------------------------------------------------
__global__ __launch_bounds__(256) void ln_kernel(
    const float* __restrict__ proj, const ushort* __restrict__ hsrc,
    const float* __restrict__ lng, const float* __restrict__ lnb,
    float* __restrict__ outp)
{
    const int m = blockIdx.x;           // b*512 + s
    const int j = threadIdx.x;
    const int b = m >> 9, s = m & 511;
    const size_t oidx = (size_t)(s * 32 + b) * 256 + j;
    const float y = proj[(size_t)m * 256 + j] + b2f(hsrc[oidx]);
    float sum = y, sq = y * y;
    #pragma unroll
    for (int off = 32; off >= 1; off >>= 1) {
        sum += __shfl_xor(sum, off, 64);
        sq += __shfl_xor(sq, off, 64);
    }
    __shared__ float r1[4], r2[4];
    const int wv = j >> 6;
    if ((j & 63) == 0) { r1[wv] = sum; r2[wv] = sq; }
    __syncthreads();
    const float ts = r1[0] + r1[1] + r1[2] + r1[3];
    const float tq = r2[0] + r2[1] + r2[2] + r2[3];
    const float mean = ts * (1.f / 256.f);
    const float var = tq * (1.f / 256.f) - mean * mean;
    const float o = (y - mean) * rsqrtf(var + 1e-5f) * lng[j] + lnb[j];
    outp[oidx] = o;
}

extern "C" void kernel_launch(void* const* d_in, const int* in_sizes, int n_in,
                              void* d_out, int out_size, void* d_ws, size_t ws_size,
                              hipStream_t stream) {
    (void)in_sizes; (void)n_in; (void)out_size; (void)ws_size;
    const float* x   = (const float*)d_in[0];
    const float* Wi  = (const float*)d_in[1];
    const float* bi  = (const float*)d_in[2];
    const float* Wh  = (const float*)d_in[3];
    const float* bh  = (const float*)d_in[4];
    const float* Wt  = (const float*)d_in[5];
    const float* bt  = (const float*)d_in[6];
    const float* Wq  = (const float*)d_in[7];
    const float* bq  = (const float*)d_in[8];
    const float* Wk  = (const float*)d_in[9];
    const float* bk  = (const float*)d_in[10];
    const float* Wv  = (const float*)d_in[11];
    const float* bv  = (const float*)d_in[12];
    const float* Wo  = (const float*)d_in[13];
    const float* bo  = (const float*)d_in[14];
    const float* rp  = (const float*)d_in[15];
    const float* lng = (const float*)d_in[16];
    const float* lnb = (const float*)d_in[17];
    float* outp = (float*)d_out;

    float* ws = (float*)d_ws;
    // pool [0, 20971520): gx fp32 [16384,1280] during pre-scan/scan; attention
    // scratch afterwards (q/kk/v fp32, pj fp32, o16 bf16).
    float* gx    = ws;
    float* q_ws  = ws;
    float* kk_ws = ws + 4194304;
    float* v_ws  = ws + 8388608;
    float* pj_ws = ws + 12582912;
    ushort* o16  = (ushort*)(ws + 16777216);     // [16384,256] bf16
    ushort* hner16 = (ushort*)(ws + 20971520);   // [S,B,256] bf16
    ushort* hre16  = (ushort*)(ws + 23068672);
    uint32_t* Wh8 = (uint32_t*)(ws + 25165824);  // [16][1280][8] f16 pairs
    uint32_t* Wt8 = (uint32_t*)(ws + 25329664);  // [48][256][8] f16 pairs
    ushort* Wq16 = (ushort*)(ws + 25427968);     // [3,256,256] bf16
    ushort* Wk16 = (ushort*)(ws + 25526272);
    ushort* Wv16 = (ushort*)(ws + 25624576);
    ushort* Wo16 = (ushort*)(ws + 25722880);     // ends 25821184 (<= r5 footprint)

    // d_out doubles as pre-scan scratch (validated only after final ln writes):
    ushort* x16  = (ushort*)outp;                // [16384,768] bf16 (6291456 f)
    ushort* Wi16 = (ushort*)(outp + 6291456);    // [1280,768] bf16 (491520 f)
    float* bsum  = outp + 7307264;               // [1280] fp32 (bi + bh)

    // 0) weight prep: direct f16 packs (no transpose pass) + bf16 GEMM operands
    pack8d_kernel<<<dim3(640), 256, 0, stream>>>(Wh, 256, Wh8, 128, 1280);
    pack8d_kernel<<<dim3(384), 256, 0, stream>>>(Wt, 768, Wt8, 384, 256);
    addvec_kernel<<<dim3(5), 256, 0, stream>>>(bi, bh, bsum, 1280);
    cvt_bf16x2_kernel<<<dim3(4096), 256, 0, stream>>>(x, x16, 12582912, Wi, Wi16, 983040);
    cvt_bf16x4_kernel<<<dim3(3072), 256, 0, stream>>>(
        Wq, Wk, Wv, Wo, Wq16, Wk16, Wv16, Wo16, 196608);

    // 1) gates_x = x @ Wi.T + (bi + bh)   [16384,1280]  (MFMA, 128x64, BK=64)
    mfma_gemm128_kernel<<<dim3(128, 20), 256, 0, stream>>>(
        x16, Wi16, bsum, gx, 1280, 768);

    // 2) sequential scan (one block per batch element)
    scan_kernel<<<dim3(32), dim3(1024), 0, stream>>>(gx, Wh8, Wt8, bt, hner16, hre16);

    // 3) three attentions: (h_ner,0), (h_re,1), (h_re,2)
    for (int i = 0; i < 3; i++) {
        const ushort* src16 = (i == 0) ? hner16 : hre16;
        qkv_gemm128_kernel<<<dim3(128, 4), 256, 0, stream>>>(
            src16, Wq16 + (size_t)i * 65536, Wk16 + (size_t)i * 65536,
            Wv16 + (size_t)i * 65536, bq + i * 256, bk + i * 256, bv + i * 256,
            rp + (size_t)i * 131072, q_ws, kk_ws, v_ws);
        attn_kernel<<<dim3(256), dim3(512), 0, stream>>>(q_ws, kk_ws, v_ws, o16);
        mfma_gemm128_kernel<<<dim3(128, 4), 256, 0, stream>>>(
            o16, Wo16 + (size_t)i * 65536, bo + i * 256, pj_ws, 256, 256);
        ln_kernel<<<dim3(16384), dim3(256), 0, stream>>>(
            pj_ws, src16, lng, lnb, outp + (size_t)i * 4194304);
    }
}

// Round 12
// 5701.767 us; speedup vs baseline: 2.1831x; 1.0393x over previous
//
#include <hip/hip_runtime.h>
#include <hip/hip_bf16.h>

// Dims: S=512, B=32, I=768, H=256, NH=8, HD=32, ML=512
#define SDIM 512
#define BDIM 32

typedef _Float16 v2h __attribute__((ext_vector_type(2)));
typedef short bf16x8 __attribute__((ext_vector_type(8)));
typedef float f32x4 __attribute__((ext_vector_type(4)));

__device__ __forceinline__ float b2f(ushort u) {
    union { uint32_t i; float f; } v; v.i = ((uint32_t)u) << 16; return v.f;
}
__device__ __forceinline__ ushort f2b(float f) {
    union { float f; uint32_t i; } v; v.f = f;
    uint32_t u = v.i;
    return (ushort)((u + 0x7fffu + ((u >> 16) & 1u)) >> 16);  // RNE
}
__device__ __forceinline__ ushort f2h(float f) {
    union { _Float16 h; ushort u; } v; v.h = (_Float16)f; return v.u;
}
// 2 f16 MACs in one VALU op (fp32 accumulate)
__device__ __forceinline__ float dot2(uint32_t w, uint32_t h, float acc) {
#if __has_builtin(__builtin_amdgcn_fdot2)
    union { uint32_t u; v2h v; } a, b;
    a.u = w; b.u = h;
    return __builtin_amdgcn_fdot2(a.v, b.v, acc, false);
#else
    union { uint32_t u; v2h v; } a, b;
    a.u = w; b.u = h;
    return acc + (float)a.v.x * (float)b.v.x + (float)a.v.y * (float)b.v.y;
#endif
}
// fast tanh: 1 - 2/(exp(2x)+1)
__device__ __forceinline__ float ftanh(float x) {
    const float t = __expf(2.f * x);
    return 1.f - 2.f * __builtin_amdgcn_rcpf(t + 1.f);
}

// 8 f16-pairs (16 k) of CONTIGUOUS weights against packed h from LDS.
#define DCHUNK8C(WQ, HQ, ACC)                                                  \
    {                                                                          \
        uint4 wA = *(const uint4*)(WQ);                                        \
        uint4 wB = *(const uint4*)((WQ) + 4);                                  \
        uint4 hA = *(const uint4*)(HQ);                                        \
        uint4 hB = *(const uint4*)((HQ) + 4);                                  \
        ACC = dot2(wA.x, hA.x, ACC);                                           \
        ACC = dot2(wA.y, hA.y, ACC);                                           \
        ACC = dot2(wA.z, hA.z, ACC);                                           \
        ACC = dot2(wA.w, hA.w, ACC);                                           \
        ACC = dot2(wB.x, hB.x, ACC);                                           \
        ACC = dot2(wB.y, hB.y, ACC);                                           \
        ACC = dot2(wB.z, hB.z, ACC);                                           \
        ACC = dot2(wB.w, hB.w, ACC);                                           \
    }

// ---------------------------------------------------------------------------
// Pack k-major f16 pairs DIRECTLY from the untransposed weight (src[j][2p]):
// out[(p>>3)*J*8 + j*8 + (p&7)]. Thread map: p fastest -> coalesced src pairs.
// ---------------------------------------------------------------------------
__global__ __launch_bounds__(256) void pack8d_kernel(
    const float* __restrict__ src, int ld, uint32_t* __restrict__ out, int P, int J)
{
    const int idx = blockIdx.x * 256 + threadIdx.x;
    if (idx >= P * J) return;
    const int j = idx / P, p = idx - j * P;
    const ushort lo = f2h(src[(size_t)j * ld + 2 * p]);
    const ushort hi = f2h(src[(size_t)j * ld + 2 * p + 1]);
    out[(((size_t)(p >> 3) * J + j) << 3) + (p & 7)] = ((uint32_t)hi << 16) | lo;
}

// ---------------------------------------------------------------------------
// fp32 -> bf16 converts: two arrays (grid-stride) / four equal arrays
// ---------------------------------------------------------------------------
__global__ __launch_bounds__(256) void cvt_bf16x2_kernel(
    const float* __restrict__ a, ushort* __restrict__ oa, int na,
    const float* __restrict__ b, ushort* __restrict__ ob, int nb)
{
    const int stride = gridDim.x * 256;
    for (int i = blockIdx.x * 256 + threadIdx.x; i < na + nb; i += stride) {
        if (i < na) oa[i] = f2b(a[i]);
        else ob[i - na] = f2b(b[i - na]);
    }
}
__global__ __launch_bounds__(256) void cvt_bf16x4_kernel(
    const float* __restrict__ a, const float* __restrict__ b,
    const float* __restrict__ c, const float* __restrict__ d,
    ushort* __restrict__ oa, ushort* __restrict__ ob,
    ushort* __restrict__ oc, ushort* __restrict__ od, int n)
{
    const int i = blockIdx.x * 256 + threadIdx.x;
    if (i >= 4 * n) return;
    const int which = i / n, j = i - which * n;
    const float* s = which == 0 ? a : which == 1 ? b : which == 2 ? c : d;
    ushort* o = which == 0 ? oa : which == 1 ? ob : which == 2 ? oc : od;
    o[j] = f2b(s[j]);
}

// ---------------------------------------------------------------------------
// o = a + b elementwise (bias fuse: bi + bh)
// ---------------------------------------------------------------------------
__global__ __launch_bounds__(256) void addvec_kernel(
    const float* __restrict__ a, const float* __restrict__ b,
    float* __restrict__ o, int n)
{
    const int i = blockIdx.x * 256 + threadIdx.x;
    if (i < n) o[i] = a[i] + b[i];
}

// ---------------------------------------------------------------------------
// MFMA bf16 GEMM, 128x64 tile, BK=64 (16 MFMA/wave per stage).
// C[m,n] = sum_k A[m,k]*B[n,k] + bias[n].
// ---------------------------------------------------------------------------
__global__ __launch_bounds__(256) void mfma_gemm128_kernel(
    const ushort* __restrict__ A16, const ushort* __restrict__ B16,
    const float* __restrict__ bias, float* __restrict__ C, int N, int K)
{
    __shared__ ushort As[128][72];   // +8 pad: 2-way-max bank aliasing
    __shared__ ushort Bs[64][72];
    const int tid = threadIdx.x;
    const int tile_m = blockIdx.x * 128, tile_n = blockIdx.y * 64;
    const int ra = tid >> 1, ca = (tid & 1) * 32;   // A: 128 rows x 64 cols
    const int rb = tid >> 2, cb = (tid & 3) * 16;   // B: 64 rows x 64 cols
    const int w = tid >> 6, lane = tid & 63;
    const int mi = lane & 15, quad = lane >> 4;
    f32x4 acc[2][4] = {};

    for (int k0 = 0; k0 < K; k0 += 64) {
        const uint4* ap = (const uint4*)(A16 + (size_t)(tile_m + ra) * K + k0 + ca);
        *(uint4*)&As[ra][ca]      = ap[0];
        *(uint4*)&As[ra][ca + 8]  = ap[1];
        *(uint4*)&As[ra][ca + 16] = ap[2];
        *(uint4*)&As[ra][ca + 24] = ap[3];
        const uint4* bp = (const uint4*)(B16 + (size_t)(tile_n + rb) * K + k0 + cb);
        *(uint4*)&Bs[rb][cb]     = bp[0];
        *(uint4*)&Bs[rb][cb + 8] = bp[1];
        __syncthreads();
        #pragma unroll
        for (int kk = 0; kk < 64; kk += 32) {
            const bf16x8 af0 = *(const bf16x8*)&As[w * 32 + mi][quad * 8 + kk];
            const bf16x8 af1 = *(const bf16x8*)&As[w * 32 + 16 + mi][quad * 8 + kk];
            #pragma unroll
            for (int j = 0; j < 4; j++) {
                const bf16x8 bf = *(const bf16x8*)&Bs[j * 16 + mi][quad * 8 + kk];
                acc[0][j] = __builtin_amdgcn_mfma_f32_16x16x32_bf16(af0, bf, acc[0][j], 0, 0, 0);
                acc[1][j] = __builtin_amdgcn_mfma_f32_16x16x32_bf16(af1, bf, acc[1][j], 0, 0, 0);
            }
        }
        __syncthreads();
    }
    #pragma unroll
    for (int j = 0; j < 4; j++) {
        const int gn = tile_n + j * 16 + mi;
        const float bv = bias[gn];
        #pragma unroll
        for (int f = 0; f < 2; f++) {
            #pragma unroll
            for (int rr = 0; rr < 4; rr++) {
                const int gm = tile_m + w * 32 + f * 16 + quad * 4 + rr;
                C[(size_t)gm * N + gn] = acc[f][j][rr] + bv;
            }
        }
    }
}

// ---------------------------------------------------------------------------
// Fused QKV GEMM, 128x64 tile, BK=64: one A-stage (ASWAP), 3 B operands,
// 48 MFMA per stage. K=N=256. relpos folded into K output.
// ---------------------------------------------------------------------------
__global__ __launch_bounds__(256) void qkv_gemm128_kernel(
    const ushort* __restrict__ A16,
    const ushort* __restrict__ Wq, const ushort* __restrict__ Wk,
    const ushort* __restrict__ Wv,
    const float* __restrict__ bq, const float* __restrict__ bk,
    const float* __restrict__ bv, const float* __restrict__ rp,
    float* __restrict__ qo, float* __restrict__ ko, float* __restrict__ vo)
{
    __shared__ ushort As[128][72];
    __shared__ ushort Bs[3][64][72];
    const int tid = threadIdx.x;
    const int tile_m = blockIdx.x * 128, tile_n = blockIdx.y * 64;
    const int ra = tid >> 1, ca = (tid & 1) * 32;
    const int am = tile_m + ra;
    const int ar = (am & (SDIM - 1)) * BDIM + (am >> 9);   // ASWAP
    const int rb = tid >> 2, cb = (tid & 3) * 16;
    const int bn = tile_n + rb;
    const int w = tid >> 6, lane = tid & 63;
    const int mi = lane & 15, quad = lane >> 4;
    f32x4 acc[3][2][4] = {};

    for (int k0 = 0; k0 < 256; k0 += 64) {
        const uint4* ap = (const uint4*)(A16 + (size_t)ar * 256 + k0 + ca);
        *(uint4*)&As[ra][ca]      = ap[0];
        *(uint4*)&As[ra][ca + 8]  = ap[1];
        *(uint4*)&As[ra][ca + 16] = ap[2];
        *(uint4*)&As[ra][ca + 24] = ap[3];
        const uint4* qp = (const uint4*)(Wq + (size_t)bn * 256 + k0 + cb);
        *(uint4*)&Bs[0][rb][cb]     = qp[0];
        *(uint4*)&Bs[0][rb][cb + 8] = qp[1];
        const uint4* kp = (const uint4*)(Wk + (size_t)bn * 256 + k0 + cb);
        *(uint4*)&Bs[1][rb][cb]     = kp[0];
        *(uint4*)&Bs[1][rb][cb + 8] = kp[1];
        const uint4* vp = (const uint4*)(Wv + (size_t)bn * 256 + k0 + cb);
        *(uint4*)&Bs[2][rb][cb]     = vp[0];
        *(uint4*)&Bs[2][rb][cb + 8] = vp[1];
        __syncthreads();
        #pragma unroll
        for (int kk = 0; kk < 64; kk += 32) {
            const bf16x8 af0 = *(const bf16x8*)&As[w * 32 + mi][quad * 8 + kk];
            const bf16x8 af1 = *(const bf16x8*)&As[w * 32 + 16 + mi][quad * 8 + kk];
            #pragma unroll
            for (int z = 0; z < 3; z++) {
                #pragma unroll
                for (int j = 0; j < 4; j++) {
                    const bf16x8 bf = *(const bf16x8*)&Bs[z][j * 16 + mi][quad * 8 + kk];
                    acc[z][0][j] = __builtin_amdgcn_mfma_f32_16x16x32_bf16(af0, bf, acc[z][0][j], 0, 0, 0);
                    acc[z][1][j] = __builtin_amdgcn_mfma_f32_16x16x32_bf16(af1, bf, acc[z][1][j], 0, 0, 0);
                }
            }
        }
        __syncthreads();
    }
    #pragma unroll
    for (int z = 0; z < 3; z++) {
        const float* bias = (z == 0) ? bq : (z == 1) ? bk : bv;
        float* out = (z == 0) ? qo : (z == 1) ? ko : vo;
        #pragma unroll
        for (int j = 0; j < 4; j++) {
            const int gn = tile_n + j * 16 + mi;
            const float bb = bias[gn];
            #pragma unroll
            for (int f = 0; f < 2; f++) {
                #pragma unroll
                for (int rr = 0; rr < 4; rr++) {
                    const int gm = tile_m + w * 32 + f * 16 + quad * 4 + rr;
                    float v = acc[z][f][j][rr] + bb;
                    if (z == 1) {
                        const int sgm = gm & (SDIM - 1);
                        v += rp[((gn >> 5) << 14) + (sgm << 5) + (gn & 31)];
                    }
                    out[(size_t)gm * 256 + gn] = v;
                }
            }
        }
    }
}

// ---------------------------------------------------------------------------
// Fused out-projection + residual + LayerNorm. 64x256 tile (full rows), so
// each wave owns 16 complete output rows -> LN reduces over 16 j-regs per
// lane + 4-step shfl within the quad's 16 lanes. Removes the pj round-trip.
// C/D layout (verified): col=lane&15, row=quad*4+rr.
// r11 NaN bugfix: B-stage must write ALL 64 columns (8 uint4s, was 4).
// ---------------------------------------------------------------------------
__global__ __launch_bounds__(256) void oproj_ln_kernel(
    const ushort* __restrict__ A16,   // o16 [16384,256] bf16 (m = b*512+s)
    const ushort* __restrict__ W16,   // Wo16 [256,256] bf16
    const float* __restrict__ bo_, const ushort* __restrict__ hsrc,
    const float* __restrict__ lng, const float* __restrict__ lnb,
    float* __restrict__ outp)
{
    __shared__ ushort As[64][72];
    __shared__ ushort Bs[256][72];
    const int tid = threadIdx.x;
    const int tile_m = blockIdx.x * 64;
    const int ra = tid >> 2, ca = (tid & 3) * 16;   // A: 64 rows x 64 cols
    const int w = tid >> 6, lane = tid & 63;
    const int mi = lane & 15, quad = lane >> 4;
    f32x4 acc[16] = {};

    for (int k0 = 0; k0 < 256; k0 += 64) {
        const uint4* ap = (const uint4*)(A16 + (size_t)(tile_m + ra) * 256 + k0 + ca);
        *(uint4*)&As[ra][ca]     = ap[0];
        *(uint4*)&As[ra][ca + 8] = ap[1];
        const uint4* bp = (const uint4*)(W16 + (size_t)tid * 256 + k0);
        #pragma unroll
        for (int u = 0; u < 8; u++)
            *(uint4*)&Bs[tid][u * 8] = bp[u];
        __syncthreads();
        #pragma unroll
        for (int kk = 0; kk < 64; kk += 32) {
            const bf16x8 af = *(const bf16x8*)&As[w * 16 + mi][quad * 8 + kk];
            #pragma unroll
            for (int j = 0; j < 16; j++) {
                const bf16x8 bf = *(const bf16x8*)&Bs[j * 16 + mi][quad * 8 + kk];
                acc[j] = __builtin_amdgcn_mfma_f32_16x16x32_bf16(af, bf, acc[j], 0, 0, 0);
            }
        }
        __syncthreads();
    }
    // epilogue: per row (w*16 + quad*4 + rr): bias + residual, LN, store
    #pragma unroll
    for (int rr = 0; rr < 4; rr++) {
        const int gm = tile_m + w * 16 + quad * 4 + rr;
        const size_t sb = (size_t)((gm & (SDIM - 1)) * BDIM + (gm >> 9)) * 256;
        float y[16];
        float sum = 0.f, sq = 0.f;
        #pragma unroll
        for (int j = 0; j < 16; j++) {
            const int col = j * 16 + mi;
            const float v = acc[j][rr] + bo_[col] + b2f(hsrc[sb + col]);
            y[j] = v; sum += v; sq += v * v;
        }
        #pragma unroll
        for (int off = 8; off >= 1; off >>= 1) {
            sum += __shfl_xor(sum, off, 64);
            sq  += __shfl_xor(sq, off, 64);
        }
        const float mean = sum * (1.f / 256.f);
        const float var = sq * (1.f / 256.f) - mean * mean;
        const float rs = rsqrtf(var + 1e-5f);
        #pragma unroll
        for (int j = 0; j < 16; j++) {
            const int col = j * 16 + mi;
            outp[sb + col] = (y[j] - mean) * rs * lng[col] + lnb[col];
        }
    }
}

// ---------------------------------------------------------------------------
// Sequential PFN scan — r1-EXACT structure (proven 4.19 ms; structural floor).
// Falsified alternatives: cross-CU split (r3, sync-latency), register stash
// (r2/r6/r9, all spill at the 64-VGPR allocator cap), LDS stash (r7, null).
// DO NOT raise live-register demand in this kernel.
// ---------------------------------------------------------------------------
__global__ __launch_bounds__(1024) void scan_kernel(
    const float* __restrict__ gx,       // [S,B,1280] precomputed x@Wi.T+bi+bh
    const uint32_t* __restrict__ Wh8,   // [16][1280][8] f16 pairs
    const uint32_t* __restrict__ Wt8,   // [48][256][8] f16 pairs
    const float* __restrict__ bt,       // [256]
    ushort* __restrict__ h_ner,         // [S,B,256] bf16
    ushort* __restrict__ h_re)          // [S,B,256] bf16
{
    const int b = blockIdx.x;
    const int tid = threadIdx.x;
    __shared__ float cs[256], g[1280], ext[1024];
    __shared__ alignas(16) uint32_t hs_pk[128];
    __shared__ alignas(16) uint32_t cat_pk[384];
    __shared__ float rsum[16];
    if (tid < 256) cs[tid] = 0.f;
    if (tid < 128) hs_pk[tid] = 0u;
    __syncthreads();
    const int lane = tid & 63;
    const int ch = tid >> 8;            // cumsoftmax chunk 0..3
    const int wch = (tid >> 6) & 3;     // wave within chunk
    const int er = tid & 255;
    const int ep = tid >> 8;
    const uint32_t* wmain = Wh8 + (size_t)tid * 8;
    const uint32_t* wext  = Wh8 + ((size_t)(ep * 4) * 1280 + 1024 + er) * 8;
    const uint32_t* wtp   = Wt8 + ((size_t)(ep * 12) * 256 + er) * 8;

    for (int t = 0; t < SDIM; t++) {
        const float* gxr = gx + (size_t)(t * BDIM + b) * 1280;
        // ---- gates = gx + h @ Wh.T (rows 0..1023, full k per thread) ----
        {
            float a0 = 0.f, a1 = 0.f;
            #pragma unroll 2
            for (int q8 = 0; q8 < 16; q8 += 2) {
                DCHUNK8C(wmain + (size_t)q8 * (1280 * 8), hs_pk + q8 * 8, a0);
                DCHUNK8C(wmain + (size_t)(q8 + 1) * (1280 * 8), hs_pk + q8 * 8 + 8, a1);
            }
            g[tid] = gxr[tid] + a0 + a1;
        }
        {   // rows 1024..1279, k split 4 ways; ep==0 folds the gx term in
            float ae = (ep == 0) ? gxr[1024 + er] : 0.f;
            #pragma unroll
            for (int i = 0; i < 4; i++)
                DCHUNK8C(wext + (size_t)i * (1280 * 8), hs_pk + (ep * 4 + i) * 8, ae);
            ext[ep * 256 + er] = ae;
        }
        __syncthreads();
        // ---- c = tanh(chunk0); cumsoftmax on chunks 1..4 (no max-sub) ----
        if (tid < 256) g[tid] = ftanh(g[tid]);
        float v;
        if (tid >= 768) {   // finish reduction for gate rows 1024..1279
            const int r_ = tid - 768;
            v = ext[r_] + ext[256 + r_] + ext[512 + r_] + ext[768 + r_];
        } else {
            v = g[256 + tid];
        }
        const float e = __expf(v);
        float wsum = e;
        #pragma unroll
        for (int off = 32; off >= 1; off >>= 1) wsum += __shfl_xor(wsum, off, 64);
        if (lane == 0) rsum[ch * 4 + wch] = wsum;
        float cum = e;   // inclusive wave scan
        #pragma unroll
        for (int off = 1; off <= 32; off <<= 1) {
            float tsh = __shfl_up(cum, (unsigned)off, 64);
            if (lane >= off) cum += tsh;
        }
        __syncthreads();
        const float tot = rsum[ch * 4] + rsum[ch * 4 + 1] + rsum[ch * 4 + 2] + rsum[ch * 4 + 3];
        float prev = 0.f;
        if (wch > 0) prev += rsum[ch * 4];
        if (wch > 1) prev += rsum[ch * 4 + 1];
        if (wch > 2) prev += rsum[ch * 4 + 2];
        float r = (cum + prev) * __builtin_amdgcn_rcpf(tot);
        if (ch == 0 || ch == 2) r = 1.f - r;   // eg_* = 1 - cumsoftmax
        g[256 + tid] = r;
        __syncthreads();
        // ---- combine gates -> c_re, c_ner, share; emit h_ner/h_re (bf16) ----
        if (tid < 256) {
            const float c = g[tid];
            const float egi = g[256 + tid], rgi = g[512 + tid];
            const float egc = g[768 + tid], rgc = g[1024 + tid];
            const float cin = cs[tid];
            const float ovc = rgc * egc, upc = rgc - ovc, dnc = egc - ovc;
            const float ovi = rgi * egi, upi = rgi - ovi, dni = egi - ovi;
            const float share = ovi * cin + ovc * c;
            const float cre = upi * cin + upc * c + share;
            const float cner = dni * cin + dnc * c + share;
            ((_Float16*)cat_pk)[tid]       = (_Float16)cre;
            ((_Float16*)cat_pk)[256 + tid] = (_Float16)cner;
            ((_Float16*)cat_pk)[512 + tid] = (_Float16)share;
            const size_t ob = (size_t)(t * BDIM + b) * 256 + tid;
            h_re[ob] = f2b(ftanh(cre));
            h_ner[ob] = f2b(ftanh(cner));
        }
        __syncthreads();
        // ---- c_out = cat @ Wt.T + bt (4 k-partials of 96 pairs per output) ----
        {
            float s0 = 0.f, s1 = 0.f;
            #pragma unroll 2
            for (int i = 0; i < 12; i += 2) {
                DCHUNK8C(wtp + (size_t)i * (256 * 8), cat_pk + (ep * 12 + i) * 8, s0);
                DCHUNK8C(wtp + (size_t)(i + 1) * (256 * 8), cat_pk + (ep * 12 + i + 1) * 8, s1);
            }
            g[ep * 256 + er] = s0 + s1;
        }
        __syncthreads();
        if (tid < 256) {
            const float co = g[tid] + g[256 + tid] + g[512 + tid] + g[768 + tid] + bt[tid];
            cs[tid] = co;
            ((_Float16*)hs_pk)[tid] = (_Float16)ftanh(co);
        }
        __syncthreads();
    }
}

// ---------------------------------------------------------------------------
// Attention for one (b, head, q-half): scores = q·(k+relpos) (relpos folded
// into kk_ws), softmax, PV. Two blocks per (b,n) -> 2 blocks/CU, hiding the
// per-q-iter barrier drains. Output bf16 for the MFMA out-projection.
// ---------------------------------------------------------------------------
__global__ __launch_bounds__(512) void attn_kernel(
    const float* __restrict__ q_ws, const float* __restrict__ kk_ws,
    const float* __restrict__ v_ws, ushort* __restrict__ o16)
{
    __shared__ float sc[8 * 516];   // 8 q-rows x 512 probs, stride 516 (bank pad)
    __shared__ float ps[8 * 256];   // PV partials per wave
    __shared__ float sinv[8];
    const int b = blockIdx.x >> 4;
    const int n = (blockIdx.x >> 1) & 7;
    const int qh = blockIdx.x & 1;
    const int tid = threadIdx.x;
    const int w = tid >> 6, lane = tid & 63;
    const int ki = w * 64 + lane;
    float kv[32];
    {
        const float4* kp = (const float4*)(kk_ws + (size_t)(b * 512 + ki) * 256 + n * 32);
        #pragma unroll
        for (int d4 = 0; d4 < 8; d4++) {
            float4 x = kp[d4];
            kv[4 * d4] = x.x; kv[4 * d4 + 1] = x.y; kv[4 * d4 + 2] = x.z; kv[4 * d4 + 3] = x.w;
        }
    }
    const int rr = lane >> 3, dq = lane & 7;

    for (int q0 = qh * 256; q0 < qh * 256 + 256; q0 += 8) {
        const float* qbase = q_ws + (size_t)(b * 512 + q0) * 256 + n * 32;
        #pragma unroll 1
        for (int r = 0; r < 8; r++) {
            const float4* q4 = (const float4*)(qbase + r * 256);   // wave-uniform
            float s0 = 0.f, s1 = 0.f;
            #pragma unroll
            for (int d4 = 0; d4 < 8; d4 += 2) {
                const float4 qa = q4[d4];
                const float4 qb = q4[d4 + 1];
                s0 += qa.x * kv[4 * d4] + qa.y * kv[4 * d4 + 1]
                    + qa.z * kv[4 * d4 + 2] + qa.w * kv[4 * d4 + 3];
                s1 += qb.x * kv[4 * d4 + 4] + qb.y * kv[4 * d4 + 5]
                    + qb.z * kv[4 * d4 + 6] + qb.w * kv[4 * d4 + 7];
            }
            sc[r * 516 + ki] = s0 + s1;
        }
        __syncthreads();
        // softmax of row w by wave w
        {
            float* row = sc + w * 516;
            float4 a = ((const float4*)row)[lane];
            float4 c4 = ((const float4*)row)[lane + 64];
            float mx = fmaxf(fmaxf(fmaxf(a.x, a.y), fmaxf(a.z, a.w)),
                             fmaxf(fmaxf(c4.x, c4.y), fmaxf(c4.z, c4.w)));
            #pragma unroll
            for (int off = 32; off >= 1; off >>= 1) mx = fmaxf(mx, __shfl_xor(mx, off, 64));
            a.x = __expf(a.x - mx); a.y = __expf(a.y - mx);
            a.z = __expf(a.z - mx); a.w = __expf(a.w - mx);
            c4.x = __expf(c4.x - mx); c4.y = __expf(c4.y - mx);
            c4.z = __expf(c4.z - mx); c4.w = __expf(c4.w - mx);
            float sm = a.x + a.y + a.z + a.w + c4.x + c4.y + c4.z + c4.w;
            #pragma unroll
            for (int off = 32; off >= 1; off >>= 1) sm += __shfl_xor(sm, off, 64);
            ((float4*)row)[lane] = a;
            ((float4*)row)[lane + 64] = c4;
            if (lane == 0) sinv[w] = 1.f / sm;
        }
        __syncthreads();
        // PV: wave w covers ki in [w*64, w*64+64); lane -> (row rr, 4 dims dq*4)
        {
            float4 acc0 = {0.f, 0.f, 0.f, 0.f};
            float4 acc1 = {0.f, 0.f, 0.f, 0.f};
            const float* erow = sc + rr * 516 + w * 64;
            const float* vbase = v_ws + (size_t)(b * 512 + w * 64) * 256 + n * 32 + dq * 4;
            #pragma unroll 4
            for (int j = 0; j < 64; j += 2) {
                const float e0 = erow[j], e1 = erow[j + 1];
                float4 v0 = *(const float4*)(vbase + (size_t)j * 256);
                float4 v1 = *(const float4*)(vbase + (size_t)(j + 1) * 256);
                acc0.x += e0 * v0.x; acc0.y += e0 * v0.y;
                acc0.z += e0 * v0.z; acc0.w += e0 * v0.w;
                acc1.x += e1 * v1.x; acc1.y += e1 * v1.y;
                acc1.z += e1 * v1.z; acc1.w += e1 * v1.w;
            }
            float4 acc = {acc0.x + acc1.x, acc0.y + acc1.y,
                          acc0.z + acc1.z, acc0.w + acc1.w};
            ((float4*)ps)[tid] = acc;
        }
        __syncthreads();
        if (tid < 256) {
            const int r2 = tid >> 5, d = tid & 31;
            float s = 0.f;
            #pragma unroll
            for (int ww = 0; ww < 8; ww++) s += ps[ww * 256 + r2 * 32 + d];
            o16[(size_t)(b * 512 + q0 + r2) * 256 + n * 32 + d] = f2b(s * sinv[r2]);
        }
        __syncthreads();
    }
}

extern "C" void kernel_launch(void* const* d_in, const int* in_sizes, int n_in,
                              void* d_out, int out_size, void* d_ws, size_t ws_size,
                              hipStream_t stream) {
    (void)in_sizes; (void)n_in; (void)out_size; (void)ws_size;
    const float* x   = (const float*)d_in[0];
    const float* Wi  = (const float*)d_in[1];
    const float* bi  = (const float*)d_in[2];
    const float* Wh  = (const float*)d_in[3];
    const float* bh  = (const float*)d_in[4];
    const float* Wt  = (const float*)d_in[5];
    const float* bt  = (const float*)d_in[6];
    const float* Wq  = (const float*)d_in[7];
    const float* bq  = (const float*)d_in[8];
    const float* Wk  = (const float*)d_in[9];
    const float* bk  = (const float*)d_in[10];
    const float* Wv  = (const float*)d_in[11];
    const float* bv  = (const float*)d_in[12];
    const float* Wo  = (const float*)d_in[13];
    const float* bo  = (const float*)d_in[14];
    const float* rp  = (const float*)d_in[15];
    const float* lng = (const float*)d_in[16];
    const float* lnb = (const float*)d_in[17];
    float* outp = (float*)d_out;

    float* ws = (float*)d_ws;
    // pool [0, 20971520): gx fp32 [16384,1280] during pre-scan/scan; attention
    // scratch afterwards (q/kk/v fp32, o16 bf16).
    float* gx    = ws;
    float* q_ws  = ws;
    float* kk_ws = ws + 4194304;
    float* v_ws  = ws + 8388608;
    ushort* o16  = (ushort*)(ws + 16777216);     // [16384,256] bf16
    ushort* hner16 = (ushort*)(ws + 20971520);   // [S,B,256] bf16
    ushort* hre16  = (ushort*)(ws + 23068672);
    uint32_t* Wh8 = (uint32_t*)(ws + 25165824);  // [16][1280][8] f16 pairs
    uint32_t* Wt8 = (uint32_t*)(ws + 25329664);  // [48][256][8] f16 pairs
    ushort* Wq16 = (ushort*)(ws + 25427968);     // [3,256,256] bf16
    ushort* Wk16 = (ushort*)(ws + 25526272);
    ushort* Wv16 = (ushort*)(ws + 25624576);
    ushort* Wo16 = (ushort*)(ws + 25722880);     // ends 25821184 (<= r5 footprint)

    // d_out doubles as pre-scan scratch (validated only after final ln writes):
    ushort* x16  = (ushort*)outp;                // [16384,768] bf16 (6291456 f)
    ushort* Wi16 = (ushort*)(outp + 6291456);    // [1280,768] bf16 (491520 f)
    float* bsum  = outp + 7307264;               // [1280] fp32 (bi + bh)

    // 0) weight prep: direct f16 packs (no transpose pass) + bf16 GEMM operands
    pack8d_kernel<<<dim3(640), 256, 0, stream>>>(Wh, 256, Wh8, 128, 1280);
    pack8d_kernel<<<dim3(384), 256, 0, stream>>>(Wt, 768, Wt8, 384, 256);
    addvec_kernel<<<dim3(5), 256, 0, stream>>>(bi, bh, bsum, 1280);
    cvt_bf16x2_kernel<<<dim3(4096), 256, 0, stream>>>(x, x16, 12582912, Wi, Wi16, 983040);
    cvt_bf16x4_kernel<<<dim3(3072), 256, 0, stream>>>(
        Wq, Wk, Wv, Wo, Wq16, Wk16, Wv16, Wo16, 196608);

    // 1) gates_x = x @ Wi.T + (bi + bh)   [16384,1280]  (MFMA, 128x64, BK=64)
    mfma_gemm128_kernel<<<dim3(128, 20), 256, 0, stream>>>(
        x16, Wi16, bsum, gx, 1280, 768);

    // 2) sequential scan (one block per batch element)
    scan_kernel<<<dim3(32), dim3(1024), 0, stream>>>(gx, Wh8, Wt8, bt, hner16, hre16);

    // 3) three attentions: (h_ner,0), (h_re,1), (h_re,2)
    for (int i = 0; i < 3; i++) {
        const ushort* src16 = (i == 0) ? hner16 : hre16;
        qkv_gemm128_kernel<<<dim3(128, 4), 256, 0, stream>>>(
            src16, Wq16 + (size_t)i * 65536, Wk16 + (size_t)i * 65536,
            Wv16 + (size_t)i * 65536, bq + i * 256, bk + i * 256, bv + i * 256,
            rp + (size_t)i * 131072, q_ws, kk_ws, v_ws);
        attn_kernel<<<dim3(512), dim3(512), 0, stream>>>(q_ws, kk_ws, v_ws, o16);
        oproj_ln_kernel<<<dim3(256), dim3(256), 0, stream>>>(
            o16, Wo16 + (size_t)i * 65536, bo + i * 256, src16,
            lng, lnb, outp + (size_t)i * 4194304);
    }
}